// Round 5
// baseline (2116.227 us; speedup 1.0000x reference)
//
#include <hip/hip_runtime.h>
#include <hip/hip_fp16.h>
#include <stdint.h>

#define HH 256
#define WW 1216
#define BB 2
#define CC 64
#define IPIX (HH*WW)
#define NPIX (BB*IPIX)
#define NBLK 1216

typedef __attribute__((ext_vector_type(8))) __bf16 bf16x8;
typedef __attribute__((ext_vector_type(4))) __bf16 bf16x4;
typedef __attribute__((ext_vector_type(4))) float floatx4;
typedef __attribute__((ext_vector_type(4))) _Float16 half4;

__device__ __forceinline__ float sigm(float x) { return 1.f / (1.f + __expf(-x)); }

// layer order: aff7(24), aff5(16), aff3(8), att7(6), att5(6), att3(6), att1(6), mask(6)
constexpr int LSTART_H[9] = {0,24,40,48,54,60,66,72,78};

// 7x7 tap -> aff plane index (-1 = center)
constexpr int PLANE[49] = {
  0, 1, 2, 3, 4, 5, 6,
  7,24,25,26,27,28, 8,
  9,29,40,41,42,30,10,
 11,31,43,-1,44,32,12,
 13,33,45,46,47,34,14,
 15,35,36,37,38,39,16,
 17,18,19,20,21,22,23};
// 7x7 tap -> kernel class: 0='7', 1='5', 2='3', 3='1'
constexpr int KCLS[49] = {
 0,0,0,0,0,0,0,
 0,1,1,1,1,1,0,
 0,1,2,2,2,1,0,
 0,1,2,3,2,1,0,
 0,1,2,2,2,1,0,
 0,1,1,1,1,1,0,
 0,0,0,0,0,0,0};
// the 48 non-center taps in order
constexpr int TAPNC[48] = {
  0,1,2,3,4,5,6,7,8,9,10,11,12,13,14,15,16,17,18,19,20,21,22,23,
  25,26,27,28,29,30,31,32,33,34,35,36,37,38,39,40,41,42,43,44,45,46,47,48};

struct WPtrs {
    const float* w[8];
    const float* s[8];
    const float* b[8];
};

// ---------------- K0: pack weights into MFMA A-fragment layout (bf16); zero barrier ctrs ----
__global__ void k_pack(WPtrs wp, __bf16* __restrict__ wpk,
                       float* __restrict__ s_all, float* __restrict__ b_all,
                       int* __restrict__ bar) {
    int idx = blockIdx.x * blockDim.x + threadIdx.x;
    if (idx < 8) bar[idx] = 0;
    if (idx < 18 * 5 * 64) {
        int kk = idx / (5 * 64);
        int r = idx - kk * 5 * 64;
        int t = r >> 6, lane = r & 63;
        int m = t * 16 + (lane & 15);
        int L = 0, o = 0;
        bool valid_m = (m < 78);
        if (valid_m) {
            for (int i = 0; i < 8; i++) if (m >= LSTART_H[i]) { L = i; o = m - LSTART_H[i]; }
        }
        __bf16 vals[8];
        for (int j = 0; j < 8; j++) {
            int k = kk * 32 + ((lane >> 4) * 8) + j;
            int tap = k >> 6, c = k & 63;
            float w = valid_m ? wp.w[L][(o * 64 + c) * 9 + tap] : 0.f;
            vals[j] = (__bf16)w;
        }
        for (int j = 0; j < 8; j++) wpk[(size_t)idx * 8 + j] = vals[j];
    }
    if (idx < 80) {
        int m = idx;
        float sv = 0.f, bv = 0.f;
        if (m < 78) {
            int L = 0, o = 0;
            for (int i = 0; i < 8; i++) if (m >= LSTART_H[i]) { L = i; o = m - LSTART_H[i]; }
            sv = wp.s[L][o]; bv = wp.b[L][o];
        }
        s_all[m] = sv; b_all[m] = bv;
    }
}

// ---------------- K1: conv as implicit GEMM; weights LDS double-buffered ----------------
// Feature read DIRECTLY from fp32 NCHW (no cvt pre-pass): per (cg,pos) 8 coalesced dword
// loads across channel planes, converted to bf16 during LDS staging.
__global__ __launch_bounds__(256, 4) void k_conv(const float* __restrict__ feat,
        const float* __restrict__ d00, const __bf16* __restrict__ wpk,
        const float* __restrict__ s_all, const float* __restrict__ b_all,
        __bf16* __restrict__ afx, __bf16* __restrict__ attp, __bf16* __restrict__ maskp,
        float* __restrict__ stp) {
    __shared__ __bf16 sh[6 * 34 * 72];
    __shared__ __bf16 wlds[2 * 2560];
    const int tid = threadIdx.x;
    // XCD-aware swizzle
    int flat = blockIdx.x + 38 * (blockIdx.y + 64 * blockIdx.z);
    int nf = (flat & 7) * 608 + (flat >> 3);
    int bx = nf % 38; int r2 = nf / 38;
    const int x0 = bx * 32, y0 = (r2 & 63) * 4, b = r2 >> 6;

    // prefetch weight panel 0 (5120 B)
    {
        bf16x8 w0 = *(const bf16x8*)(wpk + (size_t)tid * 8);
        *(bf16x8*)(wlds + tid * 8) = w0;
        if (tid < 64) {
            bf16x8 w1 = *(const bf16x8*)(wpk + 2048 + (size_t)tid * 8);
            *(bf16x8*)(wlds + 2048 + tid * 8) = w1;
        }
    }
    // stage feature tile: pos lane-fast for coalescing within channel planes
    {
        const float* fb = feat + (size_t)b * CC * IPIX;
        for (int idx = tid; idx < 204 * 8; idx += 256) {
            int pos = idx % 204, cg = idx / 204;
            int row = pos / 34, x = pos - row * 34;
            int gy = y0 + row - 1, gx = x0 + x - 1;
            bf16x8 pk;
#pragma unroll
            for (int j = 0; j < 8; j++) pk[j] = (__bf16)0.f;
            if (gy >= 0 && gy < HH && gx >= 0 && gx < WW) {
                const float* fp0 = fb + (size_t)(cg * 8) * IPIX + (size_t)gy * WW + gx;
#pragma unroll
                for (int j = 0; j < 8; j++) pk[j] = (__bf16)fp0[(size_t)j * IPIX];
            }
            *(bf16x8*)(sh + pos * 72 + cg * 8) = pk;
        }
    }
    __syncthreads();

    const int wave = tid >> 6, lane = tid & 63;
    const int n = lane & 15, g = lane >> 4;

    floatx4 acc[5][2];
#pragma unroll
    for (int t = 0; t < 5; t++)
#pragma unroll
        for (int q = 0; q < 2; q++) acc[t][q] = (floatx4)(0.f);

#pragma unroll
    for (int kk = 0; kk < 18; kk++) {
        bf16x8 wt0, wt1;
        if (kk < 17) {
            wt0 = *(const bf16x8*)(wpk + (size_t)(kk + 1) * 2560 + tid * 8);
            if (tid < 64) wt1 = *(const bf16x8*)(wpk + (size_t)(kk + 1) * 2560 + 2048 + tid * 8);
        }
        const int tap = kk >> 1;
        const int dy = tap / 3 - 1, dx = tap % 3 - 1;
        const int c0 = (kk & 1) * 32 + g * 8;
        bf16x8 bfr[2];
        const int rowb = wave + 1 + dy;
        const int colb = 1 + dx + n;
#pragma unroll
        for (int q = 0; q < 2; q++)
            bfr[q] = *(const bf16x8*)(sh + ((rowb * 34) + colb + q * 16) * 72 + c0);
        bf16x8 afr[5];
        const __bf16* wb = wlds + (kk & 1) * 2560 + lane * 8;
#pragma unroll
        for (int t = 0; t < 5; t++) afr[t] = *(const bf16x8*)(wb + t * 512);
#pragma unroll
        for (int t = 0; t < 5; t++)
#pragma unroll
            for (int q = 0; q < 2; q++)
                acc[t][q] = __builtin_amdgcn_mfma_f32_16x16x32_bf16(afr[t], bfr[q], acc[t][q], 0, 0, 0);
        if (kk < 17) {
            *(bf16x8*)(wlds + ((kk + 1) & 1) * 2560 + tid * 8) = wt0;
            if (tid < 64) *(bf16x8*)(wlds + ((kk + 1) & 1) * 2560 + 2048 + tid * 8) = wt1;
        }
        __syncthreads();
    }

    // phase 1: scale/bias + stats
    const int pix_base = b * IPIX + (y0 + wave) * WW + x0 + n;
    float p7[2] = {0,0}, t7[2] = {0,0};
    float p5[2] = {0,0}, t5[2] = {0,0};
    float p3[2] = {0,0}, t3[2] = {0,0};

#pragma unroll
    for (int t = 0; t < 5; t++) {
        const floatx4 sv = *(const floatx4*)(s_all + t * 16 + 4 * g);
        const floatx4 bv = *(const floatx4*)(b_all + t * 16 + 4 * g);
#pragma unroll
        for (int q = 0; q < 2; q++) {
#pragma unroll
            for (int reg = 0; reg < 4; reg++) {
                const int m = t * 16 + 4 * g + reg;
                const float v = fmaf(acc[t][q][reg], sv[reg], bv[reg]);
                if (m < 24)                { p7[q] += fabsf(v); t7[q] += v; }
                else if (m < 40)           { p5[q] += fabsf(v); t5[q] += v; }
                else if (m < 48)           { p3[q] += fabsf(v); t3[q] += v; }
                const float outv = (m < 48) ? v : sigm(v);
                sh[m * 132 + wave * 32 + n + q * 16] = (__bf16)outv;
            }
        }
    }
#pragma unroll
    for (int q = 0; q < 2; q++) {
        p7[q] += __shfl_xor(p7[q], 16); p7[q] += __shfl_xor(p7[q], 32);
        t7[q] += __shfl_xor(t7[q], 16); t7[q] += __shfl_xor(t7[q], 32);
        p5[q] += __shfl_xor(p5[q], 16); p5[q] += __shfl_xor(p5[q], 32);
        t5[q] += __shfl_xor(t5[q], 16); t5[q] += __shfl_xor(t5[q], 32);
        p3[q] += __shfl_xor(p3[q], 16); p3[q] += __shfl_xor(p3[q], 32);
        t3[q] += __shfl_xor(t3[q], 16); t3[q] += __shfl_xor(t3[q], 32);
    }
    if (g == 0) {
#pragma unroll
        for (int q = 0; q < 2; q++) {
            const int pixq = pix_base + q * 16;
            floatx4 s0 = {p7[q], p5[q], p3[q], t7[q]};
            floatx4 s1 = {t5[q], t3[q], 0.f, 0.f};
            *(floatx4*)(stp + (size_t)pixq * 8)     = s0;
            *(floatx4*)(stp + (size_t)pixq * 8 + 4) = s1;
        }
    }
    __syncthreads();

    // phase 2a: per-pixel tap-ordered aff pack (contiguous 16-B stores)
    {
        const int pxi = tid >> 1;
        const int hf = tid & 1;
        const int prow2 = pxi >> 5, pcol2 = pxi & 31;
        const int pix2 = b * IPIX + (y0 + prow2) * WW + x0 + pcol2;
#pragma unroll
        for (int k = 0; k < 3; k++) {
            bf16x8 v;
#pragma unroll
            for (int e = 0; e < 8; e++) {
                const int jj = hf * 24 + k * 8 + e;
                v[e] = sh[PLANE[TAPNC[jj]] * 132 + pxi];
            }
            *(bf16x8*)(afx + (size_t)pix2 * 48 + hf * 24 + k * 8) = v;
        }
    }

    // phase 2b: att/mask transpose-read, coalesced stores
    const int px = tid & 127;
    const int grp = tid >> 7;
    const int prow = px >> 5, pcol = px & 31;
    const int pix = b * IPIX + (y0 + prow) * WW + x0 + pcol;
    const float d00v = d00[pix];
    const float valid = (d00v > 0.f) ? 1.f : 0.f;
#pragma unroll
    for (int j = 0; j < 6; j += 2) {
        const int it = j + grp;
        bf16x4 av = { sh[(48 + it) * 132 + px], sh[(54 + it) * 132 + px],
                      sh[(60 + it) * 132 + px], sh[(66 + it) * 132 + px] };
        *(bf16x4*)(attp + ((size_t)it * NPIX + pix) * 4) = av;
        maskp[(size_t)it * NPIX + pix] = (__bf16)((float)sh[(72 + it) * 132 + px] * valid);
    }
}

// ---------------- K1b: afx -> afy slot-wise shift: afy[o][jj] = afx[o+(3-i,3-j)][jj] ------
__global__ __launch_bounds__(256) void k_trans(const __bf16* __restrict__ afx,
                                               __bf16* __restrict__ afy) {
    __shared__ unsigned short rec[532 * 50];   // 25-dword stride: conflict-free gather
    const int tid = threadIdx.x;
    int flat = blockIdx.x + 38 * (blockIdx.y + 32 * blockIdx.z);
    int nf = (flat & 7) * 304 + (flat >> 3);
    int bx = nf % 38; int r2 = nf / 38;
    const int x0 = bx * 32, y0 = (r2 & 31) * 8, b = r2 >> 5;
    const int ib = b * IPIX;

    const uint32_t* afx32 = (const uint32_t*)afx;
    uint32_t* rec32 = (uint32_t*)rec;
    for (int idx = tid; idx < 532 * 24; idx += 256) {
        const int d = idx % 24, rc = idx / 24;
        const int ly = rc / 38, lx = rc - ly * 38;
        const int gy = y0 + ly - 3, gx = x0 + lx - 3;
        uint32_t v = 0u;
        if (gy >= 0 && gy < HH && gx >= 0 && gx < WW)
            v = afx32[(size_t)(ib + gy * WW + gx) * 24 + d];
        rec32[rc * 25 + d] = v;
    }
    __syncthreads();

    const int pcol = tid & 31, prow = tid >> 5;
    const int pix = ib + (y0 + prow) * WW + x0 + pcol;
    const __bf16* recb = (const __bf16*)rec;
#pragma unroll
    for (int k = 0; k < 6; k++) {
        bf16x8 v;
#pragma unroll
        for (int e = 0; e < 8; e++) {
            const int jj = k * 8 + e;
            const int t = TAPNC[jj];
            const int i = t / 7, j = t % 7;
            const int rc = (prow + 6 - i) * 38 + (pcol + 6 - j);
            v[e] = recb[rc * 50 + jj];
        }
        *(bf16x8*)(afy + (size_t)pix * 48 + k * 8) = v;
    }
}

// ---------------- K2 (once): per-pixel, per-iter guide ratios r_k and g0*d0 ----------------
__global__ __launch_bounds__(256) void k_rg(const __bf16* __restrict__ attp,
        const float* __restrict__ stp, const float* __restrict__ d0,
        _Float16* __restrict__ rp, float* __restrict__ gd) {
    int g = blockIdx.x * blockDim.x + threadIdx.x;
    if (g >= NPIX) return;
    const floatx4 s0 = *(const floatx4*)(stp + (size_t)g * 8);
    const floatx4 s1 = *(const floatx4*)(stp + (size_t)g * 8 + 4);
    const float S7 = s0[0], S5 = s0[1], S3 = s0[2], T7 = s0[3], T5 = s1[0], T3 = s1[1];
    const float d0v = d0[g];
#pragma unroll
    for (int it = 0; it < 6; it++) {
        bf16x4 a = *(const bf16x4*)(attp + ((size_t)it * NPIX + g) * 4);
        float a7 = (float)a[0], a5 = (float)a[1], a3 = (float)a[2], a1 = (float)a[3];
        float denom = a7 * S7 + a5 * S5 + a3 * S3 + a1;
        float inv = 1.f / denom;
        float r7 = a7 * inv, r5 = a5 * inv, r3 = a3 * inv, r1 = a1 * inv;
        float g0 = 1.f - (r7 * T7 + r5 * T5 + r3 * T3 + r1);
        half4 rv = {(_Float16)r7, (_Float16)r5, (_Float16)r3, (_Float16)r1};
        *(half4*)(rp + ((size_t)it * NPIX + g) * 4) = rv;
        gd[(size_t)it * NPIX + g] = g0 * d0v;
    }
}

// ---------------- K3 persistent: all 6 iterations, A-records in VGPRs, MANUAL grid barrier --
// Grid = 1216 blocks exactly; launch_bounds(256,5) -> 5 blocks/CU x 256 CU = 1280 >= 1216
// co-resident (LDS 15.7 KB, VGPR capped 96). Barrier: per-iter agent-scope counter + spin
// (bounded). Capturable by hipGraph (plain kernel launch, no cooperative API).
#define SPL 984
__global__ __launch_bounds__(256, 5) void k_pers(const _Float16* __restrict__ rp,
        const float* __restrict__ gd, const float* __restrict__ d0,
        const __bf16* __restrict__ afy, const __bf16* __restrict__ maskp,
        const float* __restrict__ d00,
        float* __restrict__ dtA, float* __restrict__ dtB, int* __restrict__ bar) {
    __shared__ float sps[4 * SPL];
    const int tid = threadIdx.x;
    const int id = blockIdx.x;
    const int nf = (id & 7) * 152 + (id >> 3);     // 1216 = 8*152, bijective XCD swizzle
    const int b = nf / 608; const int r = nf - b * 608;
    const int by = r / 19, bx = r - by * 19;
    const int x0 = bx * 64, y0 = by * 8;
    const int ib = b * IPIX;
    const int ox = tid & 63, py = tid >> 6;        // outputs (py,ox) and (py+4,ox)

    const int pixA = ib + (y0 + py) * WW + x0 + ox;
    const int pixB = pixA + 4 * WW;

    // prologue: persist A-records + d00 (the once-only 60 MB afy read)
    const __bf16* ra = afy + (size_t)pixA * 48;
    const __bf16* rb = afy + (size_t)pixB * 48;
    bf16x8 Aa0 = *(const bf16x8*)(ra),      Aa1 = *(const bf16x8*)(ra + 8);
    bf16x8 Aa2 = *(const bf16x8*)(ra + 16), Aa3 = *(const bf16x8*)(ra + 24);
    bf16x8 Aa4 = *(const bf16x8*)(ra + 32), Aa5 = *(const bf16x8*)(ra + 40);
    bf16x8 Ab0 = *(const bf16x8*)(rb),      Ab1 = *(const bf16x8*)(rb + 8);
    bf16x8 Ab2 = *(const bf16x8*)(rb + 16), Ab3 = *(const bf16x8*)(rb + 24);
    bf16x8 Ab4 = *(const bf16x8*)(rb + 32), Ab5 = *(const bf16x8*)(rb + 40);
    const float dva = d00[pixA], dvb = d00[pixB];

    auto recdot = [&](bf16x8 A0, bf16x8 A1, bf16x8 A2, bf16x8 A3, bf16x8 A4, bf16x8 A5,
                      int cb) -> float {
        float a0 = sps[3 * SPL + cb + 3 * 70 + 3];  // center: r1*dt + g0*d0
        float a1 = 0.f, a2 = 0.f, a3 = 0.f;
#pragma unroll
        for (int jj = 0; jj < 48; jj++) {
            const int t = TAPNC[jj];
            const int i = t / 7, j = t % 7;
            const int off = (6 - i) * 70 + (6 - j);
            float av;
            switch (jj >> 3) {
                case 0: av = (float)A0[jj & 7]; break;
                case 1: av = (float)A1[jj & 7]; break;
                case 2: av = (float)A2[jj & 7]; break;
                case 3: av = (float)A3[jj & 7]; break;
                case 4: av = (float)A4[jj & 7]; break;
                default: av = (float)A5[jj & 7]; break;
            }
            const float pv = sps[KCLS[t] * SPL + cb + off];
            switch (jj & 3) {
                case 0: a0 = fmaf(av, pv, a0); break;
                case 1: a1 = fmaf(av, pv, a1); break;
                case 2: a2 = fmaf(av, pv, a2); break;
                default: a3 = fmaf(av, pv, a3); break;
            }
        }
        return (a0 + a1) + (a2 + a3);
    };

#pragma unroll
    for (int it = 0; it < 6; it++) {
        const float* src = (it == 0) ? d0 : ((it & 1) ? dtA : dtB);
        float* dst = (it & 1) ? dtB : dtA;

        // stage P planes over 70x14 halo region
#pragma unroll
        for (int r4 = 0; r4 < 4; r4++) {
            const int idx = tid + r4 * 256;
            if (idx < 980) {
                const int ly = idx / 70, lx = idx - ly * 70;
                const int gy = y0 + ly - 3, gx = x0 + lx - 3;
                float c0 = 0.f, c1 = 0.f, c2 = 0.f, c3 = 0.f;
                if (gy >= 0 && gy < HH && gx >= 0 && gx < WW) {
                    const int q = ib + gy * WW + gx;
                    const half4 rv = *(const half4*)(rp + ((size_t)it * NPIX + q) * 4);
                    const float dtv = src[q];
                    const float gdv = gd[(size_t)it * NPIX + q];
                    c0 = (float)rv[0] * dtv; c1 = (float)rv[1] * dtv;
                    c2 = (float)rv[2] * dtv; c3 = (float)rv[3] * dtv + gdv;
                }
                sps[idx] = c0; sps[SPL + idx] = c1;
                sps[2 * SPL + idx] = c2; sps[3 * SPL + idx] = c3;
            }
        }
        __syncthreads();

        const int cbA = py * 70 + ox;
        const float accA = recdot(Aa0, Aa1, Aa2, Aa3, Aa4, Aa5, cbA);
        const float accB = recdot(Ab0, Ab1, Ab2, Ab3, Ab4, Ab5, cbA + 4 * 70);
        const float ma = (float)maskp[(size_t)it * NPIX + pixA];
        const float mb = (float)maskp[(size_t)it * NPIX + pixB];
        dst[pixA] = ma * dva + (1.f - ma) * accA;
        dst[pixB] = mb * dvb + (1.f - mb) * accB;

        if (it < 5) {
            // ---- manual grid barrier ----
            __syncthreads();            // all block threads' stores issued (vmcnt drained)
            __threadfence();            // release: write back to device scope (cross-XCD)
            if (tid == 0) {
                __hip_atomic_fetch_add(&bar[it], 1, __ATOMIC_ACQ_REL,
                                       __HIP_MEMORY_SCOPE_AGENT);
                int spins = 0;
                while (__hip_atomic_load(&bar[it], __ATOMIC_ACQUIRE,
                                         __HIP_MEMORY_SCOPE_AGENT) < NBLK) {
                    __builtin_amdgcn_s_sleep(8);
                    if (++spins > (1 << 20)) break;   // bounded: fail visibly, never hang
                }
            }
            __syncthreads();
            __threadfence();            // acquire: invalidate stale L1/L2 for next-iter reads
        }
    }
}

// ---------------- launch ----------------
extern "C" void kernel_launch(void* const* d_in, const int* in_sizes, int n_in,
                              void* d_out, int out_size, void* d_ws, size_t ws_size,
                              hipStream_t stream) {
    const float* feat = (const float*)d_in[0];
    const float* d0   = (const float*)d_in[1];
    const float* d00  = (const float*)d_in[2];
    WPtrs wp;
    for (int l = 0; l < 8; l++) {
        wp.w[l] = (const float*)d_in[3 + 3 * l];
        wp.s[l] = (const float*)d_in[4 + 3 * l];
        wp.b[l] = (const float*)d_in[5 + 3 * l];
    }
    __bf16*   wsb   = (__bf16*)d_ws;
    __bf16*   afy   = wsb;                                   // NPIX x 48 bf16 (own-record)
    __bf16*   attp  = afy + (size_t)48 * NPIX;               // 6*NPIX bf16x4
    __bf16*   msk_b = attp + (size_t)24 * NPIX;              // 6 planes bf16
    float*    stp   = (float*)(msk_b + (size_t)6 * NPIX);    // NPIX*8 fp32
    float*    dtA   = stp + (size_t)8 * NPIX;                // 1 fp32 plane (ping)
    __bf16*   wpk   = (__bf16*)(dtA + (size_t)NPIX);         // 92160 B packed weights
    float*    s_all = (float*)(wpk + 18 * 5 * 64 * 8);
    float*    b_all = s_all + 80;
    int*      bar   = (int*)(b_all + 80);                    // 8 barrier counters
    // region Y: afx (dead after k_trans) aliased over rp+gd (written after, by k_rg)
    char*     Y     = (char*)(bar + 16);
    __bf16*   afx   = (__bf16*)Y;                            // NPIX x 48 bf16 (59.8 MB)
    _Float16* rp    = (_Float16*)Y;                          // 6*NPIX fp16x4 (29.9 MB)
    float*    gd    = (float*)(Y + (size_t)24 * NPIX * 2);   // 6*NPIX fp32 (14.9 MB)
    float*    dtB   = (float*)d_out;                         // pong (final iter target)

    hipLaunchKernelGGL(k_pack, dim3(23), dim3(256), 0, stream, wp, wpk, s_all, b_all, bar);
    hipLaunchKernelGGL(k_conv, dim3(38, 64, 2), dim3(256), 0, stream,
                       feat, d00, wpk, s_all, b_all, afx, attp, msk_b, stp);
    hipLaunchKernelGGL(k_trans, dim3(38, 32, 2), dim3(256), 0, stream, afx, afy);
    hipLaunchKernelGGL(k_rg, dim3(NPIX / 256), dim3(256), 0, stream,
                       attp, stp, d0, rp, gd);
    hipLaunchKernelGGL(k_pers, dim3(NBLK), dim3(256), 0, stream,
                       rp, gd, d0, afy, msk_b, d00, dtA, (float*)d_out, bar);
}

// Round 6
// 532.008 us; speedup vs baseline: 3.9778x; 3.9778x over previous
//
#include <hip/hip_runtime.h>
#include <hip/hip_fp16.h>
#include <stdint.h>

#define HH 256
#define WW 1216
#define BB 2
#define CC 64
#define IPIX (HH*WW)
#define NPIX (BB*IPIX)
// padded aff planes: left pad 32 (64B-aligned rows), right pad, 3-row halo top/bottom
#define PW 1280
#define PH 262
#define PPIX (PH*PW)               // 335360
#define PLSTRIDE (BB*PPIX)         // 670720
#define XOFF 32

typedef __attribute__((ext_vector_type(8))) __bf16 bf16x8;
typedef __attribute__((ext_vector_type(4))) __bf16 bf16x4;
typedef __attribute__((ext_vector_type(4))) float floatx4;
typedef __attribute__((ext_vector_type(4))) _Float16 half4;

__device__ __forceinline__ float sigm(float x) { return 1.f / (1.f + __expf(-x)); }

// layer order: aff7(24), aff5(16), aff3(8), att7(6), att5(6), att3(6), att1(6), mask(6)
constexpr int LSTART_H[9] = {0,24,40,48,54,60,66,72,78};

// 7x7 tap -> aff plane index (-1 = center, uses g1 with no aff factor)
constexpr int PLANE[49] = {
  0, 1, 2, 3, 4, 5, 6,
  7,24,25,26,27,28, 8,
  9,29,40,41,42,30,10,
 11,31,43,-1,44,32,12,
 13,33,45,46,47,34,14,
 15,35,36,37,38,39,16,
 17,18,19,20,21,22,23};
// 7x7 tap -> kernel class: 0='7', 1='5', 2='3', 3='1'
constexpr int KCLS[49] = {
 0,0,0,0,0,0,0,
 0,1,1,1,1,1,0,
 0,1,2,2,2,1,0,
 0,1,2,3,2,1,0,
 0,1,2,2,2,1,0,
 0,1,1,1,1,1,0,
 0,0,0,0,0,0,0};
// the 48 non-center taps in order
constexpr int TAPNC[48] = {
  0,1,2,3,4,5,6,7,8,9,10,11,12,13,14,15,16,17,18,19,20,21,22,23,
  25,26,27,28,29,30,31,32,33,34,35,36,37,38,39,40,41,42,43,44,45,46,47,48};

struct WPtrs {
    const float* w[8];
    const float* s[8];
    const float* b[8];
};

// ---------------- K0: pack weights into MFMA A-fragment layout (bf16) ----------------
__global__ void k_pack(WPtrs wp, __bf16* __restrict__ wpk,
                       float* __restrict__ s_all, float* __restrict__ b_all) {
    int idx = blockIdx.x * blockDim.x + threadIdx.x;
    if (idx < 18 * 5 * 64) {
        int kk = idx / (5 * 64);
        int r = idx - kk * 5 * 64;
        int t = r >> 6, lane = r & 63;
        int m = t * 16 + (lane & 15);
        int L = 0, o = 0;
        bool valid_m = (m < 78);
        if (valid_m) {
            for (int i = 0; i < 8; i++) if (m >= LSTART_H[i]) { L = i; o = m - LSTART_H[i]; }
        }
        __bf16 vals[8];
        for (int j = 0; j < 8; j++) {
            int k = kk * 32 + ((lane >> 4) * 8) + j;
            int tap = k >> 6, c = k & 63;
            float w = valid_m ? wp.w[L][(o * 64 + c) * 9 + tap] : 0.f;
            vals[j] = (__bf16)w;
        }
        for (int j = 0; j < 8; j++) wpk[(size_t)idx * 8 + j] = vals[j];
    }
    if (idx < 80) {
        int m = idx;
        float sv = 0.f, bv = 0.f;
        if (m < 78) {
            int L = 0, o = 0;
            for (int i = 0; i < 8; i++) if (m >= LSTART_H[i]) { L = i; o = m - LSTART_H[i]; }
            sv = wp.s[L][o]; bv = wp.b[L][o];
        }
        s_all[m] = sv; b_all[m] = bv;
    }
}

// ---------------- K0b: zero the pad borders of aff (48 padded planes) ----------------
__global__ void k_zero_pad(__bf16* __restrict__ aff_p) {
    const int perPB = 6 * PW + 256 * 16;   // 11776
    int idx = blockIdx.x * blockDim.x + threadIdx.x;
    int total = 48 * BB * perPB;
    if (idx >= total) return;
    int pbi = idx / perPB;
    int e = idx - pbi * perPB;
    int plane = pbi >> 1, b = pbi & 1;
    int r, c;
    if (e < 6 * PW) {
        int rr = e / PW; c = e - rr * PW;
        r = (rr < 3) ? rr : (259 + rr - 3);
    } else {
        int j = e - 6 * PW;
        r = 3 + (j >> 4);
        int c16 = j & 15;
        c = (c16 < 8) ? (24 + c16) : (1248 + c16 - 8);
    }
    aff_p[(size_t)plane * PLSTRIDE + (size_t)b * PPIX + r * PW + c] = (__bf16)0.f;
}

// ---------------- K0c: feature fp32 NCHW -> bf16 (b,y,x,[c]) channel-packed ----------------
__global__ __launch_bounds__(256) void k_cvt(const float* __restrict__ feat,
                                             __bf16* __restrict__ fpk) {
    const int x = blockIdx.x * 64 + (threadIdx.x & 63);
    const int half = threadIdx.x >> 6;            // 0..3
    const int y = blockIdx.y, b = blockIdx.z;
    const float* fb = feat + (size_t)b * CC * IPIX + (size_t)y * WW + x;
    __bf16* op = fpk + ((size_t)(b * IPIX + y * WW + x) << 6);
#pragma unroll
    for (int h = 0; h < 2; h++) {
        const int cg = half + h * 4;              // channel group of 8
        bf16x8 pk;
#pragma unroll
        for (int j = 0; j < 8; j++) pk[j] = (__bf16)fb[(size_t)(cg * 8 + j) * IPIX];
        *(bf16x8*)(op + cg * 8) = pk;
    }
}

// ---------------- K1: conv as implicit GEMM; weights LDS double-buffered ----------------
// Block: 256 thr = 4 waves; pixel tile 32 wide x 4 high; wave w = row w, 2 N-frags of 16.
// LDS: sh feature tile 29376 B + wlds weight dbuf 10240 B = 39616 B -> 4 blocks/CU.
__global__ __launch_bounds__(256, 4) void k_conv(const __bf16* __restrict__ fpk,
        const float* __restrict__ d00, const __bf16* __restrict__ wpk,
        const float* __restrict__ s_all, const float* __restrict__ b_all,
        __bf16* __restrict__ aff_p, __bf16* __restrict__ attp, __bf16* __restrict__ maskp,
        float* __restrict__ stp) {
    __shared__ __bf16 sh[6 * 34 * 72];
    __shared__ __bf16 wlds[2 * 2560];
    const int tid = threadIdx.x;
    // XCD-aware swizzle: contiguous y-slabs per XCD for halo L2 locality
    int flat = blockIdx.x + 38 * (blockIdx.y + 64 * blockIdx.z);
    int nf = (flat & 7) * 608 + (flat >> 3);
    int bx = nf % 38; int r2 = nf / 38;
    const int x0 = bx * 32, y0 = (r2 & 63) * 4, b = r2 >> 6;

    // prefetch weight panel 0 (5120 B)
    {
        bf16x8 w0 = *(const bf16x8*)(wpk + (size_t)tid * 8);
        *(bf16x8*)(wlds + tid * 8) = w0;
        if (tid < 64) {
            bf16x8 w1 = *(const bf16x8*)(wpk + 2048 + (size_t)tid * 8);
            *(bf16x8*)(wlds + 2048 + tid * 8) = w1;
        }
    }
    // stage feature tile from packed bf16: fully coalesced dwordx4 + ds_write_b128
    for (int idx = tid; idx < 204 * 8; idx += 256) {
        int cg = idx & 7, pos = idx >> 3;
        int row = pos / 34, x = pos - row * 34;
        int gy = y0 + row - 1, gx = x0 + x - 1;
        bf16x8 pk;
#pragma unroll
        for (int j = 0; j < 8; j++) pk[j] = (__bf16)0.f;
        if (gy >= 0 && gy < HH && gx >= 0 && gx < WW)
            pk = *(const bf16x8*)(fpk + ((size_t)(b * IPIX + gy * WW + gx) << 6) + cg * 8);
        *(bf16x8*)(sh + pos * 72 + cg * 8) = pk;
    }
    __syncthreads();

    const int wave = tid >> 6, lane = tid & 63;
    const int n = lane & 15, g = lane >> 4;

    floatx4 acc[5][2];
#pragma unroll
    for (int t = 0; t < 5; t++)
#pragma unroll
        for (int q = 0; q < 2; q++) acc[t][q] = (floatx4)(0.f);

#pragma unroll
    for (int kk = 0; kk < 18; kk++) {
        // prefetch weight panel kk+1 into registers (1-2 coalesced 16B loads/thread)
        bf16x8 wt0, wt1;
        if (kk < 17) {
            wt0 = *(const bf16x8*)(wpk + (size_t)(kk + 1) * 2560 + tid * 8);
            if (tid < 64) wt1 = *(const bf16x8*)(wpk + (size_t)(kk + 1) * 2560 + 2048 + tid * 8);
        }
        const int tap = kk >> 1;
        const int dy = tap / 3 - 1, dx = tap % 3 - 1;
        const int c0 = (kk & 1) * 32 + g * 8;
        bf16x8 bfr[2];
        const int rowb = wave + 1 + dy;
        const int colb = 1 + dx + n;
#pragma unroll
        for (int q = 0; q < 2; q++)
            bfr[q] = *(const bf16x8*)(sh + ((rowb * 34) + colb + q * 16) * 72 + c0);
        bf16x8 afr[5];
        const __bf16* wb = wlds + (kk & 1) * 2560 + lane * 8;
#pragma unroll
        for (int t = 0; t < 5; t++) afr[t] = *(const bf16x8*)(wb + t * 512);
#pragma unroll
        for (int t = 0; t < 5; t++)
#pragma unroll
            for (int q = 0; q < 2; q++)
                acc[t][q] = __builtin_amdgcn_mfma_f32_16x16x32_bf16(afr[t], bfr[q], acc[t][q], 0, 0, 0);
        if (kk < 17) {
            *(bf16x8*)(wlds + ((kk + 1) & 1) * 2560 + tid * 8) = wt0;
            if (tid < 64) *(bf16x8*)(wlds + ((kk + 1) & 1) * 2560 + 2048 + tid * 8) = wt1;
        }
        __syncthreads();
    }

    // phase 1: scale/bias + stats; bf16 results into LDS sh[m*132 + wave*32 + n + 16q]
    const int pix_base = b * IPIX + (y0 + wave) * WW + x0 + n;
    float p7[2] = {0,0}, t7[2] = {0,0};
    float p5[2] = {0,0}, t5[2] = {0,0};
    float p3[2] = {0,0}, t3[2] = {0,0};

#pragma unroll
    for (int t = 0; t < 5; t++) {
        const floatx4 sv = *(const floatx4*)(s_all + t * 16 + 4 * g);
        const floatx4 bv = *(const floatx4*)(b_all + t * 16 + 4 * g);
#pragma unroll
        for (int q = 0; q < 2; q++) {
#pragma unroll
            for (int reg = 0; reg < 4; reg++) {
                const int m = t * 16 + 4 * g + reg;
                const float v = fmaf(acc[t][q][reg], sv[reg], bv[reg]);
                if (m < 24)                { p7[q] += fabsf(v); t7[q] += v; }
                else if (m < 40)           { p5[q] += fabsf(v); t5[q] += v; }
                else if (m < 48)           { p3[q] += fabsf(v); t3[q] += v; }
                const float outv = (m < 48) ? v : sigm(v);
                sh[m * 132 + wave * 32 + n + q * 16] = (__bf16)outv;
            }
        }
    }
#pragma unroll
    for (int q = 0; q < 2; q++) {
        p7[q] += __shfl_xor(p7[q], 16); p7[q] += __shfl_xor(p7[q], 32);
        t7[q] += __shfl_xor(t7[q], 16); t7[q] += __shfl_xor(t7[q], 32);
        p5[q] += __shfl_xor(p5[q], 16); p5[q] += __shfl_xor(p5[q], 32);
        t5[q] += __shfl_xor(t5[q], 16); t5[q] += __shfl_xor(t5[q], 32);
        p3[q] += __shfl_xor(p3[q], 16); p3[q] += __shfl_xor(p3[q], 32);
        t3[q] += __shfl_xor(t3[q], 16); t3[q] += __shfl_xor(t3[q], 32);
    }
    if (g == 0) {
#pragma unroll
        for (int q = 0; q < 2; q++) {
            const int pixq = pix_base + q * 16;
            floatx4 s0 = {p7[q], p5[q], p3[q], t7[q]};
            floatx4 s1 = {t5[q], t3[q], 0.f, 0.f};
            *(floatx4*)(stp + (size_t)pixq * 8)     = s0;
            *(floatx4*)(stp + (size_t)pixq * 8 + 4) = s1;
        }
    }
    __syncthreads();

    // phase 2: transpose-read, fully coalesced stores
    const int px = tid & 127;
    const int grp = tid >> 7;
    const int prow = px >> 5, pcol = px & 31;
    const size_t ppx = (size_t)b * PPIX + (y0 + prow + 3) * PW + (x0 + pcol + XOFF);
    const int pix = b * IPIX + (y0 + prow) * WW + x0 + pcol;
#pragma unroll
    for (int m = 0; m < 48; m += 2) {
        aff_p[(size_t)(m + grp) * PLSTRIDE + ppx] = sh[(m + grp) * 132 + px];
    }
    const float d00v = d00[pix];
    const float valid = (d00v > 0.f) ? 1.f : 0.f;
#pragma unroll
    for (int j = 0; j < 6; j += 2) {
        const int it = j + grp;
        bf16x4 av = { sh[(48 + it) * 132 + px], sh[(54 + it) * 132 + px],
                      sh[(60 + it) * 132 + px], sh[(66 + it) * 132 + px] };
        *(bf16x4*)(attp + ((size_t)it * NPIX + pix) * 4) = av;
        maskp[(size_t)it * NPIX + pix] = (__bf16)((float)sh[(72 + it) * 132 + px] * valid);
    }
}

// ---------------- K2 (once): per-pixel, per-iter guide ratios r_k and g0*d0 ----------------
__global__ __launch_bounds__(256) void k_rg(const __bf16* __restrict__ attp,
        const float* __restrict__ stp, const float* __restrict__ d0,
        _Float16* __restrict__ rp, float* __restrict__ gd) {
    int g = blockIdx.x * blockDim.x + threadIdx.x;
    if (g >= NPIX) return;
    const floatx4 s0 = *(const floatx4*)(stp + (size_t)g * 8);
    const floatx4 s1 = *(const floatx4*)(stp + (size_t)g * 8 + 4);
    const float S7 = s0[0], S5 = s0[1], S3 = s0[2], T7 = s0[3], T5 = s1[0], T3 = s1[1];
    const float d0v = d0[g];
#pragma unroll
    for (int it = 0; it < 6; it++) {
        bf16x4 a = *(const bf16x4*)(attp + ((size_t)it * NPIX + g) * 4);
        float a7 = (float)a[0], a5 = (float)a[1], a3 = (float)a[2], a1 = (float)a[3];
        float denom = a7 * S7 + a5 * S5 + a3 * S3 + a1;   // > 0: a1 = sigmoid > 0
        float inv = 1.f / denom;
        float r7 = a7 * inv, r5 = a5 * inv, r3 = a3 * inv, r1 = a1 * inv;
        float g0 = 1.f - (r7 * T7 + r5 * T5 + r3 * T3 + r1);
        half4 rv = {(_Float16)r7, (_Float16)r5, (_Float16)r3, (_Float16)r1};
        *(half4*)(rp + ((size_t)it * NPIX + g) * 4) = rv;
        gd[(size_t)it * NPIX + g] = g0 * d0v;
    }
}

// ---------------- K3 (per iter): LDS p-planes + batched 49-tap gather ----------------
// Tile 32x16 outputs / 256 threads (2 outputs each, rows ty and ty+8); halo region 22x38.
// 1216 blocks -> 4.75 blocks/CU, all co-resident in one scheduling round.
__global__ __launch_bounds__(256) void k_iter(const _Float16* __restrict__ rp,
        const float* __restrict__ gd, const float* __restrict__ dt,
        const __bf16* __restrict__ aff_p, const __bf16* __restrict__ maskp,
        const float* __restrict__ d00,
        float* __restrict__ dtn, int it) {
    __shared__ float sp[5][22 * 38];
    const int tid = threadIdx.x;
    const int tx = tid & 31, ty = tid >> 5;
    int flat = blockIdx.x + 38 * (blockIdx.y + 16 * blockIdx.z);
    int nf = (flat & 7) * 152 + (flat >> 3);
    int bx = nf % 38; int r2 = nf / 38;
    const int x0 = bx * 32, y0 = (r2 & 15) * 16, b = r2 >> 4;
    const int ib = b * IPIX;

    for (int idx = tid; idx < 22 * 38; idx += 256) {
        int r = idx / 38, col = idx - r * 38;
        int gy = y0 + r - 3, gx = x0 + col - 3;
        float v7 = 0.f, v5 = 0.f, v3 = 0.f, v1 = 0.f, vb = 0.f;
        if (gy >= 0 && gy < HH && gx >= 0 && gx < WW) {
            int q = ib + gy * WW + gx;
            half4 rv = *(const half4*)(rp + ((size_t)it * NPIX + q) * 4);
            float dtv = dt[q];
            v7 = (float)rv[0] * dtv; v5 = (float)rv[1] * dtv;
            v3 = (float)rv[2] * dtv; v1 = (float)rv[3] * dtv;
            vb = gd[(size_t)it * NPIX + q];
        }
        sp[0][idx] = v7; sp[1][idx] = v5; sp[2][idx] = v3; sp[3][idx] = v1; sp[4][idx] = vb;
    }
    __syncthreads();

    const int yA = y0 + ty, yB = y0 + ty + 8;
    const int x = x0 + tx;
    const int pixA = ib + yA * WW + x;
    const int pixB = ib + yB * WW + x;
    const __bf16* apA = aff_p + (size_t)b * PPIX + (yA + 3) * PW + (x + XOFF);
    const __bf16* apB = apA + 8 * PW;
    const int cbA = (ty + 3) * 38 + (tx + 3);
    const int cbB = cbA + 8 * 38;

    // center + base for both outputs
    float accA0 = sp[4][cbA] + sp[3][cbA];
    float accA1 = 0.f, accA2 = 0.f, accA3 = 0.f;
    float accB0 = sp[4][cbB] + sp[3][cbB];
    float accB1 = 0.f, accB2 = 0.f, accB3 = 0.f;
    // 6 batches of 8 taps; 16 aff loads in flight per batch (8 per output)
#pragma unroll
    for (int bt = 0; bt < 6; bt++) {
        float a8A[8], a8B[8];
#pragma unroll
        for (int j = 0; j < 8; j++) {
            const int t = TAPNC[bt * 8 + j];
            const int dy = 3 - t / 7, dx = 3 - (t % 7);
            const ptrdiff_t po = (ptrdiff_t)PLANE[t] * PLSTRIDE + dy * PW + dx;
            a8A[j] = (float)apA[po];
            a8B[j] = (float)apB[po];
        }
#pragma unroll
        for (int j = 0; j < 8; j++) {
            const int t = TAPNC[bt * 8 + j];
            const int dy = 3 - t / 7, dx = 3 - (t % 7);
            const int off = dy * 38 + dx;
            const float pvA = sp[KCLS[t]][cbA + off];
            const float pvB = sp[KCLS[t]][cbB + off];
            switch (j & 3) {
                case 0: accA0 = fmaf(a8A[j], pvA, accA0); accB0 = fmaf(a8B[j], pvB, accB0); break;
                case 1: accA1 = fmaf(a8A[j], pvA, accA1); accB1 = fmaf(a8B[j], pvB, accB1); break;
                case 2: accA2 = fmaf(a8A[j], pvA, accA2); accB2 = fmaf(a8B[j], pvB, accB2); break;
                default: accA3 = fmaf(a8A[j], pvA, accA3); accB3 = fmaf(a8B[j], pvB, accB3); break;
            }
        }
    }
    const float accA = (accA0 + accA1) + (accA2 + accA3);
    const float accB = (accB0 + accB1) + (accB2 + accB3);
    const float mA = (float)maskp[(size_t)it * NPIX + pixA];
    const float mB = (float)maskp[(size_t)it * NPIX + pixB];
    dtn[pixA] = mA * d00[pixA] + (1.f - mA) * accA;
    dtn[pixB] = mB * d00[pixB] + (1.f - mB) * accB;
}

// ---------------- launch ----------------
extern "C" void kernel_launch(void* const* d_in, const int* in_sizes, int n_in,
                              void* d_out, int out_size, void* d_ws, size_t ws_size,
                              hipStream_t stream) {
    const float* feat = (const float*)d_in[0];
    const float* d0   = (const float*)d_in[1];
    const float* d00  = (const float*)d_in[2];
    WPtrs wp;
    for (int l = 0; l < 8; l++) {
        wp.w[l] = (const float*)d_in[3 + 3 * l];
        wp.s[l] = (const float*)d_in[4 + 3 * l];
        wp.b[l] = (const float*)d_in[5 + 3 * l];
    }
    __bf16*   wsb   = (__bf16*)d_ws;
    __bf16*   aff_p = wsb;                                   // 48 padded planes bf16
    __bf16*   attp  = aff_p + (size_t)48 * PLSTRIDE;         // 6*NPIX bf16x4
    __bf16*   msk_b = attp + (size_t)24 * NPIX;              // 6 planes bf16
    float*    stp   = (float*)(msk_b + (size_t)6 * NPIX);    // NPIX*8 fp32
    float*    dtA   = stp + (size_t)8 * NPIX;                // 1 fp32 plane (ping)
    __bf16*   wpk   = (__bf16*)(dtA + (size_t)NPIX);         // 92160 B packed weights
    float*    s_all = (float*)(wpk + 18 * 5 * 64 * 8);
    float*    b_all = s_all + 80;
    // region X: fpk (dead after k_conv) aliased over rp+gd (written after, by k_rg)
    char*     X     = (char*)(b_all + 80);
    __bf16*   fpk   = (__bf16*)X;                            // 64*NPIX bf16 (79.7 MB)
    _Float16* rp    = (_Float16*)X;                          // 6*NPIX fp16x4
    float*    gd    = (float*)(X + (size_t)24 * NPIX * 2);   // 6*NPIX fp32
    float*    dtB   = (float*)d_out;                         // pong (overwritten before reads)

    hipLaunchKernelGGL(k_pack, dim3(23), dim3(256), 0, stream, wp, wpk, s_all, b_all);
    hipLaunchKernelGGL(k_zero_pad, dim3((48 * BB * (6 * PW + 256 * 16) + 255) / 256), dim3(256),
                       0, stream, aff_p);
    hipLaunchKernelGGL(k_cvt, dim3(WW / 64, HH, BB), dim3(256), 0, stream, feat, fpk);
    hipLaunchKernelGGL(k_conv, dim3(38, 64, 2), dim3(256), 0, stream,
                       fpk, d00, wpk, s_all, b_all, aff_p, attp, msk_b, stp);
    hipLaunchKernelGGL(k_rg, dim3(NPIX / 256), dim3(256), 0, stream,
                       attp, stp, d0, rp, gd);
    const float* cur = d0;
    for (int it = 0; it < 6; ++it) {
        float* nxt = (it & 1) ? dtB : dtA;
        if (it == 5) nxt = dtB;
        hipLaunchKernelGGL(k_iter, dim3(38, 16, 2), dim3(256), 0, stream,
                           rp, gd, cur, aff_p, msk_b, d00, nxt, it);
        cur = nxt;
    }
}